// Round 12
// baseline (274.973 us; speedup 1.0000x reference)
//
#include <hip/hip_runtime.h>

// DeepGCN forward on MI355X.
// R11: bf16-only residual state -> 265us, absmax unchanged (2^-10 floor).
// R12: middle/final GEMMs were latency-bound (8 barriers/tile, 2.4 blk/CU;
// ~12us vs 3.3us streaming floor). New gemm: W (K=128) resident in LDS once
// (1 barrier), A fragments loaded DIRECTLY from global (16B contiguous per
// lane, 64B lines fully consumed) -> zero-barrier K-loop, 4 independent
// prefetchable A loads per wave. gemm1 (K=256) unchanged (scatter-hidden).
// SpMM untouched: at measured random-gather composite ceiling (4 variants).

#define DIN 256
#define HID 128
#define NCLS 64
#define VAL_DEC 1.9073486328125e-6f   // 2^-19 (val < 1/16 -> 15-bit fixed pt)
#define SB 256                         // scatter blocks / edge chunks

typedef __attribute__((ext_vector_type(8))) short bf16x8;
typedef __attribute__((ext_vector_type(4))) float f32x4;

static __device__ __forceinline__ float bf2f(unsigned int u) {
    return __uint_as_float(u << 16);
}
static __device__ __forceinline__ unsigned short f2bf(float f) {
    unsigned int i = __float_as_uint(f);
    return (unsigned short)((i + 0x7FFFu + ((i >> 16) & 1u)) >> 16);   // RNE
}
static __device__ __forceinline__ unsigned int pack2(float a, float b) {
    return (unsigned int)f2bf(a) | ((unsigned int)f2bf(b) << 16);
}

// ---------------- 1) prep (wtrans) + bucket histogram ----------------
__global__ __launch_bounds__(256) void prep_hist_kernel(
        const float* __restrict__ w1, const float* __restrict__ wm,
        const float* __restrict__ w2, unsigned short* __restrict__ w1t,
        unsigned short* __restrict__ wmt, unsigned short* __restrict__ w2t, int L,
        const int* __restrict__ erow, int* __restrict__ counts_t, int E, int NB) {
    __shared__ int cnt[256];
    const int tid = threadIdx.x;
    for (int k = tid; k < NB; k += 256) cnt[k] = 0;

    const int n1 = DIN * HID;
    const int n2 = n1 + L * HID * HID;
    const int n3 = n2 + HID * NCLS;
    for (int idx = blockIdx.x * 256 + tid; idx < n3; idx += SB * 256) {
        if (idx < n1) {
            int n = idx / DIN, k = idx - n * DIN;
            w1t[idx] = f2bf(w1[(size_t)k * HID + n]);
        } else if (idx < n2) {
            int j = idx - n1;
            int i = j / (HID * HID), r = j - i * (HID * HID);
            int n = r / HID, k = r - n * HID;
            wmt[j] = f2bf(wm[(size_t)i * HID * HID + (size_t)k * HID + n]);
        } else {
            int j = idx - n2;
            int n = j / HID, k = j - n * HID;
            w2t[j] = f2bf(w2[(size_t)k * NCLS + n]);
        }
    }
    __syncthreads();
    const int chunk = (E + SB - 1) / SB;
    const int lo = blockIdx.x * chunk;
    const int hi = min(lo + chunk, E);
    for (int e = lo + tid; e < hi; e += 256)
        atomicAdd(&cnt[erow[e] >> 8], 1);
    __syncthreads();
    for (int k = tid; k < NB; k += 256)
        counts_t[k * SB + blockIdx.x] = cnt[k];
}

// ---------------- 2) scan over counts_t (n = NB*SB) ----------------
__global__ __launch_bounds__(1024) void scan_sums_kernel(
        const int* __restrict__ a, int* __restrict__ bsums, int n) {
    __shared__ int wsum[16];
    const int lane = threadIdx.x & 63;
    const int wid  = threadIdx.x >> 6;
    int i = blockIdx.x * 1024 + threadIdx.x;
    int v = (i < n) ? a[i] : 0;
    #pragma unroll
    for (int d = 32; d >= 1; d >>= 1) v += __shfl_xor(v, d, 64);
    if (lane == 0) wsum[wid] = v;
    __syncthreads();
    if (threadIdx.x == 0) {
        int s = 0;
        #pragma unroll
        for (int w = 0; w < 16; ++w) s += wsum[w];
        bsums[blockIdx.x] = s;
    }
}

__global__ __launch_bounds__(1024) void scan_fix_kernel(
        const int* __restrict__ a, const int* __restrict__ bsums,
        int* __restrict__ out, int n, int nb) {
    __shared__ int wsum[16];
    __shared__ int bpref_s;
    const int lane = threadIdx.x & 63;
    const int wid  = threadIdx.x >> 6;
    const int b = blockIdx.x;
    if (wid == 0) {
        int v = (lane < nb && lane < b) ? bsums[lane] : 0;
        #pragma unroll
        for (int d = 32; d >= 1; d >>= 1) v += __shfl_xor(v, d, 64);
        if (lane == 0) bpref_s = v;
    }
    int i = b * 1024 + (int)threadIdx.x;
    int v = (i < n) ? a[i] : 0;
    int incl = v;
    #pragma unroll
    for (int d = 1; d < 64; d <<= 1) {
        int t = __shfl_up(incl, d, 64);
        if (lane >= d) incl += t;
    }
    if (lane == 63) wsum[wid] = incl;
    __syncthreads();
    int wpref = 0;
    #pragma unroll
    for (int w = 0; w < 16; ++w)
        if (w < wid) wpref += wsum[w];
    int excl = bpref_s + wpref + incl - v;
    if (i < n) out[i] = excl;
    if (i == n) out[n] = excl;
}

// ---------------- 4) MEGA: GEMM1 (x fp32->bf16 inline) || bucket scatter ----------------
__global__ __launch_bounds__(256) void mega_kernel(
        const float* __restrict__ x, const unsigned short* __restrict__ w1t,
        const float* __restrict__ b1, unsigned short* __restrict__ z,
        const int* __restrict__ erow, const int* __restrict__ ecol,
        const float* __restrict__ eval, const int* __restrict__ starts,
        unsigned int* __restrict__ bw, unsigned char* __restrict__ br,
        int E, int NB, int gemmBlocks) {
    const int tid = threadIdx.x;
    if ((int)blockIdx.x >= gemmBlocks) {
        __shared__ int ptr[256];
        const int sb = blockIdx.x - gemmBlocks;      // 0..SB-1
        for (int k = tid; k < NB; k += 256) ptr[k] = starts[k * SB + sb];
        __syncthreads();
        const int chunk = (E + SB - 1) / SB;
        const int lo = sb * chunk;
        const int hi = min(lo + chunk, E);
        for (int e = lo + tid; e < hi; e += 256) {
            int r = erow[e];
            int q = min((int)(eval[e] * 524288.0f + 0.5f), 32767);
            unsigned int w = ((unsigned int)ecol[e] << 15) | (unsigned int)q;
            int p = atomicAdd(&ptr[r >> 8], 1);      // LDS atomic only
            bw[p] = w;
            br[p] = (unsigned char)(r & 255);
        }
        return;
    }
    __shared__ __align__(16) unsigned short Alds[64 * 40];
    __shared__ __align__(16) unsigned short Blds[128 * 40];
    const int bm   = blockIdx.x * 64;
    const int wave = tid >> 6;
    const int lane = tid & 63;
    const int m16  = lane & 15;
    const int quad = lane >> 4;
    const int ar = tid >> 2, ac = (tid & 3) * 8;

    f32x4 acc[8] = {};
    for (int k0 = 0; k0 < DIN; k0 += 32) {
        float4 a0 = *(const float4*)&x[(size_t)(bm + ar) * DIN + k0 + ac];
        float4 a1 = *(const float4*)&x[(size_t)(bm + ar) * DIN + k0 + ac + 4];
        uint4 av;
        av.x = pack2(a0.x, a0.y); av.y = pack2(a0.z, a0.w);
        av.z = pack2(a1.x, a1.y); av.w = pack2(a1.z, a1.w);
        *(uint4*)&Alds[ar * 40 + ac] = av;
        #pragma unroll
        for (int i = 0; i < 2; ++i) {
            int c = tid + 256 * i;
            int brow = c >> 2, bc = (c & 3) * 8;
            *(uint4*)&Blds[brow * 40 + bc] = *(const uint4*)&w1t[(size_t)brow * DIN + k0 + bc];
        }
        __syncthreads();
        bf16x8 af = *(const bf16x8*)&Alds[(wave * 16 + m16) * 40 + quad * 8];
        #pragma unroll
        for (int j = 0; j < 8; ++j) {
            bf16x8 bfr = *(const bf16x8*)&Blds[(j * 16 + m16) * 40 + quad * 8];
            acc[j] = __builtin_amdgcn_mfma_f32_16x16x32_bf16(af, bfr, acc[j], 0, 0, 0);
        }
        __syncthreads();
    }
    #pragma unroll
    for (int j = 0; j < 8; ++j) {
        int col = j * 16 + m16;
        float bb = b1[col];
        #pragma unroll
        for (int r = 0; r < 4; ++r) {
            int row = bm + wave * 16 + quad * 4 + r;
            z[(size_t)row * HID + col] = f2bf(acc[j][r] + bb);
        }
    }
}

// ---------------- 5) finalize: per-bucket exact-row offs + sort ----------------
__global__ __launch_bounds__(256) void finalize_kernel(
        const int* __restrict__ starts, const unsigned int* __restrict__ bw,
        const unsigned char* __restrict__ br, unsigned int* __restrict__ edges,
        int* __restrict__ offs, int N, int NB) {
    __shared__ int cnt[256];
    __shared__ int posl[256];
    __shared__ int ws[4];
    const int tid = threadIdx.x;
    const int k = blockIdx.x;
    const int b0 = starts[k * SB];
    const int b1 = starts[(k + 1) * SB];
    cnt[tid] = 0;
    __syncthreads();
    for (int i = b0 + tid; i < b1; i += 256)
        atomicAdd(&cnt[br[i]], 1);
    __syncthreads();
    const int lane = tid & 63, wid = tid >> 6;
    int v = cnt[tid];
    int incl = v;
    #pragma unroll
    for (int d = 1; d < 64; d <<= 1) {
        int t = __shfl_up(incl, d, 64);
        if (lane >= d) incl += t;
    }
    if (lane == 63) ws[wid] = incl;
    __syncthreads();
    int wp = 0;
    #pragma unroll
    for (int w = 0; w < 4; ++w)
        if (w < wid) wp += ws[w];
    int excl = wp + incl - v;
    int g = (k << 8) + tid;
    if (g <= N) offs[g] = b0 + excl;
    posl[tid] = b0 + excl;
    __syncthreads();
    for (int i = b0 + tid; i < b1; i += 256) {
        int r = br[i];
        unsigned int w = bw[i];
        int p = atomicAdd(&posl[r], 1);
        edges[p] = w;
    }
}

// ---------------- MFMA bf16 GEMM, K=128: W resident in LDS, A direct-global ----------------
// C[N,BN] = A[N,128] @ Wt[BN,128]^T + bias.  One W-load barrier; the K-loop
// has NO barriers: lane (m16,quad) loads its A fragment (16B contiguous)
// straight from global -- 4 lanes consume each 64B line fully.
template <int BN>
__global__ __launch_bounds__(256) void gemm_mfma_kernel(
        const unsigned short* __restrict__ A, const unsigned short* __restrict__ Wt,
        const float* __restrict__ bias, unsigned short* __restrict__ C, int N) {
    constexpr int NT = BN / 16;
    constexpr int K = 128;
    __shared__ __align__(16) unsigned short Blds[BN * 136];
    const int tid  = threadIdx.x;
    const int wave = tid >> 6;
    const int lane = tid & 63;
    const int m16  = lane & 15;
    const int quad = lane >> 4;

    // stage all of Wt (BN x 128) into LDS, padded stride 136
    for (int c = tid; c < BN * 16; c += 256) {     // 16 uint4-chunks per row
        int brow = c >> 4, bc = (c & 15) * 8;
        *(uint4*)&Blds[brow * 136 + bc] = *(const uint4*)&Wt[(size_t)brow * K + bc];
    }
    __syncthreads();

    const int tiles = N >> 6;
    for (int t = blockIdx.x; t < tiles; t += gridDim.x) {
        const int arow = t * 64 + wave * 16 + m16;
        const unsigned short* ap = A + (size_t)arow * K + quad * 8;
        f32x4 acc[NT] = {};
        #pragma unroll
        for (int s = 0; s < 4; ++s) {              // K-steps of 32, no barriers
            bf16x8 af = *(const bf16x8*)(ap + s * 32);
            #pragma unroll
            for (int j = 0; j < NT; ++j) {
                bf16x8 bfr = *(const bf16x8*)&Blds[(j * 16 + m16) * 136 + s * 32 + quad * 8];
                acc[j] = __builtin_amdgcn_mfma_f32_16x16x32_bf16(af, bfr, acc[j], 0, 0, 0);
            }
        }
        #pragma unroll
        for (int j = 0; j < NT; ++j) {
            int col = j * 16 + m16;
            float bb = bias[col];
            #pragma unroll
            for (int r = 0; r < 4; ++r) {
                int row = t * 64 + wave * 16 + quad * 4 + r;
                C[(size_t)row * BN + col] = f2bf(acc[j][r] + bb);
            }
        }
    }
}

// ---------------- SpMM over bf16 z (row-major), 4B packed edges ----------------
// bf16 residual state: MODE 0: hb = bf16(relu(s))
//                      MODE 1: hb = bf16(bf2f(hb) + relu(s)*dt)
//                      MODE 2: out = s (fp32)
template <int D, int MODE>
__global__ __launch_bounds__(256) void spmm_kernel(
        const int* __restrict__ offs, const unsigned int* __restrict__ edges,
        const unsigned short* __restrict__ z,
        float* __restrict__ out, unsigned short* __restrict__ hb,
        const float* __restrict__ dt_ptr, int n) {
    int r = (int)((blockIdx.x * blockDim.x + threadIdx.x) >> 6);
    int lane = threadIdx.x & 63;
    if (r >= n) return;
    r = __builtin_amdgcn_readfirstlane(r);
    const int s = offs[r], e = offs[r + 1];
    float acc0 = 0.f, acc1 = 0.f;
    int p = s;
    if (D == 128) {
        const unsigned int* z32 = (const unsigned int*)z;
        for (; p + 8 <= e; p += 8) {
            unsigned int ev[8], g[8];
            #pragma unroll
            for (int i = 0; i < 8; ++i) ev[i] = __builtin_nontemporal_load(edges + p + i);
            #pragma unroll
            for (int i = 0; i < 8; ++i)
                g[i] = z32[(size_t)(ev[i] >> 15) * 64 + lane];
            #pragma unroll
            for (int i = 0; i < 8; ++i) {
                float v = (float)(ev[i] & 0x7fffu) * VAL_DEC;
                acc0 = fmaf(v, bf2f(g[i] & 0xffffu), acc0);
                acc1 = fmaf(v, bf2f(g[i] >> 16), acc1);
            }
        }
        for (; p < e; ++p) {
            unsigned int ev = __builtin_nontemporal_load(edges + p);
            float v = (float)(ev & 0x7fffu) * VAL_DEC;
            unsigned int g = z32[(size_t)(ev >> 15) * 64 + lane];
            acc0 = fmaf(v, bf2f(g & 0xffffu), acc0);
            acc1 = fmaf(v, bf2f(g >> 16), acc1);
        }
        unsigned int* hbw = (unsigned int*)hb + (size_t)r * 64 + lane;
        if (MODE == 2) {
            float2 o; o.x = acc0; o.y = acc1;
            *(float2*)&out[(size_t)r * 128 + 2 * lane] = o;
        } else if (MODE == 0) {
            *hbw = pack2(fmaxf(acc0, 0.f), fmaxf(acc1, 0.f));
        } else {
            float dt = *dt_ptr;
            unsigned int cur = *hbw;
            float f0 = bf2f(cur & 0xffffu) + fmaxf(acc0, 0.f) * dt;
            float f1 = bf2f(cur >> 16)    + fmaxf(acc1, 0.f) * dt;
            *hbw = pack2(f0, f1);
        }
    } else {  // D == 64 (final layer, MODE 2)
        for (; p + 8 <= e; p += 8) {
            unsigned int ev[8];
            unsigned short g[8];
            #pragma unroll
            for (int i = 0; i < 8; ++i) ev[i] = __builtin_nontemporal_load(edges + p + i);
            #pragma unroll
            for (int i = 0; i < 8; ++i)
                g[i] = z[(size_t)(ev[i] >> 15) * 64 + lane];
            #pragma unroll
            for (int i = 0; i < 8; ++i)
                acc0 = fmaf((float)(ev[i] & 0x7fffu) * VAL_DEC, bf2f(g[i]), acc0);
        }
        for (; p < e; ++p) {
            unsigned int ev = __builtin_nontemporal_load(edges + p);
            acc0 = fmaf((float)(ev & 0x7fffu) * VAL_DEC,
                        bf2f((unsigned int)z[(size_t)(ev >> 15) * 64 + lane]), acc0);
        }
        out[(size_t)r * 64 + lane] = acc0;
    }
}

extern "C" void kernel_launch(void* const* d_in, const int* in_sizes, int n_in,
                              void* d_out, int out_size, void* d_ws, size_t ws_size,
                              hipStream_t stream) {
    const float* x    = (const float*)d_in[0];
    const int*   erow = (const int*)d_in[1];
    const int*   ecol = (const int*)d_in[2];
    const float* eval = (const float*)d_in[3];
    const float* w1   = (const float*)d_in[4];
    const float* b1   = (const float*)d_in[5];
    const float* wm   = (const float*)d_in[6];
    const float* bmp  = (const float*)d_in[7];
    const float* w2   = (const float*)d_in[8];
    const float* b2   = (const float*)d_in[9];
    const float* dt   = (const float*)d_in[10];

    const int N = in_sizes[0] / DIN;       // 40000
    const int E = in_sizes[1];             // 640000
    const int L = in_sizes[7] / HID;       // 2
    const int NB = (N + 255) >> 8;         // 157 buckets

    float* outp = (float*)d_out;

    char* ws = (char*)d_ws;
    auto carve = [&](size_t bytes) -> char* {
        char* p = ws;
        ws += (bytes + 255) & ~(size_t)255;
        return p;
    };
    int*            counts = (int*)carve((size_t)(NB * SB + 1) * 4);
    int*            starts = (int*)carve((size_t)(NB * SB + 1) * 4);
    int*            bsums  = (int*)carve(64 * 4);
    int*            offs   = (int*)carve((size_t)(N + 1) * 4);
    unsigned int*   bw     = (unsigned int*)carve((size_t)E * 4);
    unsigned char*  brr    = (unsigned char*)carve((size_t)E);
    unsigned int*   edges  = (unsigned int*)carve((size_t)E * 4);
    unsigned short* z      = (unsigned short*)carve((size_t)N * HID * 2);
    unsigned short* hb     = (unsigned short*)carve((size_t)N * HID * 2);
    unsigned short* w1t    = (unsigned short*)carve((size_t)HID * DIN * 2);
    unsigned short* wmt    = (unsigned short*)carve((size_t)L * HID * HID * 2);
    unsigned short* w2t    = (unsigned short*)carve((size_t)NCLS * HID * 2);

    const int nscan   = NB * SB;                 // 40192
    const int ntiles  = (nscan + 1023) / 1024;   // 40 (covers i==nscan)
    const int gemm_blocks = N / 64;              // 625
    const int spmm_blocks = (N + 3) / 4;         // 10000

    // --- CSR build (counting sort) + prep ---
    prep_hist_kernel<<<SB, 256, 0, stream>>>(w1, wm, w2, w1t, wmt, w2t, L,
                                             erow, counts, E, NB);
    scan_sums_kernel<<<ntiles, 1024, 0, stream>>>(counts, bsums, nscan);
    scan_fix_kernel<<<ntiles, 1024, 0, stream>>>(counts, bsums, starts, nscan, ntiles);
    // --- GEMM1 || bucket scatter ---
    mega_kernel<<<gemm_blocks + SB, 256, 0, stream>>>(
        x, w1t, b1, z, erow, ecol, eval, starts, bw, brr, E, NB, gemm_blocks);
    finalize_kernel<<<NB, 256, 0, stream>>>(starts, bw, brr, edges, offs, N, NB);

    spmm_kernel<HID, 0><<<spmm_blocks, 256, 0, stream>>>(offs, edges, z, nullptr, hb, nullptr, N);

    // --- middle residual layers ---
    for (int i = 0; i < L; ++i) {
        gemm_mfma_kernel<HID><<<gemm_blocks, 256, 0, stream>>>(
            hb, wmt + (size_t)i * HID * HID, bmp + (size_t)i * HID, z, N);
        spmm_kernel<HID, 1><<<spmm_blocks, 256, 0, stream>>>(offs, edges, z, nullptr, hb, dt, N);
    }

    // --- output layer ---
    gemm_mfma_kernel<NCLS><<<gemm_blocks, 256, 0, stream>>>(hb, w2t, b2, z, N);
    spmm_kernel<NCLS, 2><<<spmm_blocks, 256, 0, stream>>>(offs, edges, z, outp, nullptr, nullptr, N);
}

// Round 13
// 265.091 us; speedup vs baseline: 1.0373x; 1.0373x over previous
//
#include <hip/hip_runtime.h>

// DeepGCN forward on MI355X — R13 = revert to R11 (best measured: 265us).
// R12 post-mortem: zero-barrier direct-global-A GEMM REGRESSED (275us) —
// the LDS-staged cooperative A load pipelines better, and the 2-barrier
// rhythm was already hidden by resident waves. Final structure:
//  - counting-sort CSR (one writer/line; fixed 20x scatter writeback amp)
//  - mega: GEMM1 (x fp32->bf16 inline, MFMA) || bucket scatter
//  - SpMM: 1 wave/row, 8-deep gathers of full 256B z rows (measured
//    random-gather composite ceiling across 4 structural variants)
//  - bf16 z + bf16 residual state; 15-bit fixed-point edge values
//  - absmax pinned at 2^-10 (bf16 z rounding floor)

#define DIN 256
#define HID 128
#define NCLS 64
#define VAL_DEC 1.9073486328125e-6f   // 2^-19 (val < 1/16 -> 15-bit fixed pt)
#define SB 256                         // scatter blocks / edge chunks

typedef __attribute__((ext_vector_type(8))) short bf16x8;
typedef __attribute__((ext_vector_type(4))) float f32x4;

static __device__ __forceinline__ float bf2f(unsigned int u) {
    return __uint_as_float(u << 16);
}
static __device__ __forceinline__ unsigned short f2bf(float f) {
    unsigned int i = __float_as_uint(f);
    return (unsigned short)((i + 0x7FFFu + ((i >> 16) & 1u)) >> 16);   // RNE
}
static __device__ __forceinline__ unsigned int pack2(float a, float b) {
    return (unsigned int)f2bf(a) | ((unsigned int)f2bf(b) << 16);
}

// ---------------- 1) prep (wtrans) + bucket histogram ----------------
__global__ __launch_bounds__(256) void prep_hist_kernel(
        const float* __restrict__ w1, const float* __restrict__ wm,
        const float* __restrict__ w2, unsigned short* __restrict__ w1t,
        unsigned short* __restrict__ wmt, unsigned short* __restrict__ w2t, int L,
        const int* __restrict__ erow, int* __restrict__ counts_t, int E, int NB) {
    __shared__ int cnt[256];
    const int tid = threadIdx.x;
    for (int k = tid; k < NB; k += 256) cnt[k] = 0;

    const int n1 = DIN * HID;
    const int n2 = n1 + L * HID * HID;
    const int n3 = n2 + HID * NCLS;
    for (int idx = blockIdx.x * 256 + tid; idx < n3; idx += SB * 256) {
        if (idx < n1) {
            int n = idx / DIN, k = idx - n * DIN;
            w1t[idx] = f2bf(w1[(size_t)k * HID + n]);
        } else if (idx < n2) {
            int j = idx - n1;
            int i = j / (HID * HID), r = j - i * (HID * HID);
            int n = r / HID, k = r - n * HID;
            wmt[j] = f2bf(wm[(size_t)i * HID * HID + (size_t)k * HID + n]);
        } else {
            int j = idx - n2;
            int n = j / HID, k = j - n * HID;
            w2t[j] = f2bf(w2[(size_t)k * NCLS + n]);
        }
    }
    __syncthreads();
    const int chunk = (E + SB - 1) / SB;
    const int lo = blockIdx.x * chunk;
    const int hi = min(lo + chunk, E);
    for (int e = lo + tid; e < hi; e += 256)
        atomicAdd(&cnt[erow[e] >> 8], 1);
    __syncthreads();
    for (int k = tid; k < NB; k += 256)
        counts_t[k * SB + blockIdx.x] = cnt[k];
}

// ---------------- 2) scan over counts_t (n = NB*SB) ----------------
__global__ __launch_bounds__(1024) void scan_sums_kernel(
        const int* __restrict__ a, int* __restrict__ bsums, int n) {
    __shared__ int wsum[16];
    const int lane = threadIdx.x & 63;
    const int wid  = threadIdx.x >> 6;
    int i = blockIdx.x * 1024 + threadIdx.x;
    int v = (i < n) ? a[i] : 0;
    #pragma unroll
    for (int d = 32; d >= 1; d >>= 1) v += __shfl_xor(v, d, 64);
    if (lane == 0) wsum[wid] = v;
    __syncthreads();
    if (threadIdx.x == 0) {
        int s = 0;
        #pragma unroll
        for (int w = 0; w < 16; ++w) s += wsum[w];
        bsums[blockIdx.x] = s;
    }
}

__global__ __launch_bounds__(1024) void scan_fix_kernel(
        const int* __restrict__ a, const int* __restrict__ bsums,
        int* __restrict__ out, int n, int nb) {
    __shared__ int wsum[16];
    __shared__ int bpref_s;
    const int lane = threadIdx.x & 63;
    const int wid  = threadIdx.x >> 6;
    const int b = blockIdx.x;
    if (wid == 0) {
        int v = (lane < nb && lane < b) ? bsums[lane] : 0;
        #pragma unroll
        for (int d = 32; d >= 1; d >>= 1) v += __shfl_xor(v, d, 64);
        if (lane == 0) bpref_s = v;
    }
    int i = b * 1024 + (int)threadIdx.x;
    int v = (i < n) ? a[i] : 0;
    int incl = v;
    #pragma unroll
    for (int d = 1; d < 64; d <<= 1) {
        int t = __shfl_up(incl, d, 64);
        if (lane >= d) incl += t;
    }
    if (lane == 63) wsum[wid] = incl;
    __syncthreads();
    int wpref = 0;
    #pragma unroll
    for (int w = 0; w < 16; ++w)
        if (w < wid) wpref += wsum[w];
    int excl = bpref_s + wpref + incl - v;
    if (i < n) out[i] = excl;
    if (i == n) out[n] = excl;
}

// ---------------- 4) MEGA: GEMM1 (x fp32->bf16 inline) || bucket scatter ----------------
__global__ __launch_bounds__(256) void mega_kernel(
        const float* __restrict__ x, const unsigned short* __restrict__ w1t,
        const float* __restrict__ b1, unsigned short* __restrict__ z,
        const int* __restrict__ erow, const int* __restrict__ ecol,
        const float* __restrict__ eval, const int* __restrict__ starts,
        unsigned int* __restrict__ bw, unsigned char* __restrict__ br,
        int E, int NB, int gemmBlocks) {
    const int tid = threadIdx.x;
    if ((int)blockIdx.x >= gemmBlocks) {
        __shared__ int ptr[256];
        const int sb = blockIdx.x - gemmBlocks;      // 0..SB-1
        for (int k = tid; k < NB; k += 256) ptr[k] = starts[k * SB + sb];
        __syncthreads();
        const int chunk = (E + SB - 1) / SB;
        const int lo = sb * chunk;
        const int hi = min(lo + chunk, E);
        for (int e = lo + tid; e < hi; e += 256) {
            int r = erow[e];
            int q = min((int)(eval[e] * 524288.0f + 0.5f), 32767);
            unsigned int w = ((unsigned int)ecol[e] << 15) | (unsigned int)q;
            int p = atomicAdd(&ptr[r >> 8], 1);      // LDS atomic only
            bw[p] = w;
            br[p] = (unsigned char)(r & 255);
        }
        return;
    }
    __shared__ __align__(16) unsigned short Alds[64 * 40];
    __shared__ __align__(16) unsigned short Blds[128 * 40];
    const int bm   = blockIdx.x * 64;
    const int wave = tid >> 6;
    const int lane = tid & 63;
    const int m16  = lane & 15;
    const int quad = lane >> 4;
    const int ar = tid >> 2, ac = (tid & 3) * 8;

    f32x4 acc[8] = {};
    for (int k0 = 0; k0 < DIN; k0 += 32) {
        float4 a0 = *(const float4*)&x[(size_t)(bm + ar) * DIN + k0 + ac];
        float4 a1 = *(const float4*)&x[(size_t)(bm + ar) * DIN + k0 + ac + 4];
        uint4 av;
        av.x = pack2(a0.x, a0.y); av.y = pack2(a0.z, a0.w);
        av.z = pack2(a1.x, a1.y); av.w = pack2(a1.z, a1.w);
        *(uint4*)&Alds[ar * 40 + ac] = av;
        #pragma unroll
        for (int i = 0; i < 2; ++i) {
            int c = tid + 256 * i;
            int brow = c >> 2, bc = (c & 3) * 8;
            *(uint4*)&Blds[brow * 40 + bc] = *(const uint4*)&w1t[(size_t)brow * DIN + k0 + bc];
        }
        __syncthreads();
        bf16x8 af = *(const bf16x8*)&Alds[(wave * 16 + m16) * 40 + quad * 8];
        #pragma unroll
        for (int j = 0; j < 8; ++j) {
            bf16x8 bfr = *(const bf16x8*)&Blds[(j * 16 + m16) * 40 + quad * 8];
            acc[j] = __builtin_amdgcn_mfma_f32_16x16x32_bf16(af, bfr, acc[j], 0, 0, 0);
        }
        __syncthreads();
    }
    #pragma unroll
    for (int j = 0; j < 8; ++j) {
        int col = j * 16 + m16;
        float bb = b1[col];
        #pragma unroll
        for (int r = 0; r < 4; ++r) {
            int row = bm + wave * 16 + quad * 4 + r;
            z[(size_t)row * HID + col] = f2bf(acc[j][r] + bb);
        }
    }
}

// ---------------- 5) finalize: per-bucket exact-row offs + sort ----------------
__global__ __launch_bounds__(256) void finalize_kernel(
        const int* __restrict__ starts, const unsigned int* __restrict__ bw,
        const unsigned char* __restrict__ br, unsigned int* __restrict__ edges,
        int* __restrict__ offs, int N, int NB) {
    __shared__ int cnt[256];
    __shared__ int posl[256];
    __shared__ int ws[4];
    const int tid = threadIdx.x;
    const int k = blockIdx.x;
    const int b0 = starts[k * SB];
    const int b1 = starts[(k + 1) * SB];
    cnt[tid] = 0;
    __syncthreads();
    for (int i = b0 + tid; i < b1; i += 256)
        atomicAdd(&cnt[br[i]], 1);
    __syncthreads();
    const int lane = tid & 63, wid = tid >> 6;
    int v = cnt[tid];
    int incl = v;
    #pragma unroll
    for (int d = 1; d < 64; d <<= 1) {
        int t = __shfl_up(incl, d, 64);
        if (lane >= d) incl += t;
    }
    if (lane == 63) ws[wid] = incl;
    __syncthreads();
    int wp = 0;
    #pragma unroll
    for (int w = 0; w < 4; ++w)
        if (w < wid) wp += ws[w];
    int excl = wp + incl - v;
    int g = (k << 8) + tid;
    if (g <= N) offs[g] = b0 + excl;
    posl[tid] = b0 + excl;
    __syncthreads();
    for (int i = b0 + tid; i < b1; i += 256) {
        int r = br[i];
        unsigned int w = bw[i];
        int p = atomicAdd(&posl[r], 1);
        edges[p] = w;
    }
}

// ---------------- MFMA bf16 GEMM (row-major A/C): C[N,BN]=A@Wt^T+bias ----------------
template <int BN>
__global__ __launch_bounds__(256) void gemm_mfma_kernel(
        const unsigned short* __restrict__ A, const unsigned short* __restrict__ Wt,
        const float* __restrict__ bias, unsigned short* __restrict__ C, int K) {
    constexpr int NT = BN / 16;
    __shared__ __align__(16) unsigned short Alds[64 * 40];
    __shared__ __align__(16) unsigned short Blds[BN * 40];
    const int tid  = threadIdx.x;
    const int bm   = blockIdx.x * 64;
    const int wave = tid >> 6;
    const int lane = tid & 63;
    const int m16  = lane & 15;
    const int quad = lane >> 4;
    const int ar = tid >> 2, ac = (tid & 3) * 8;

    f32x4 acc[NT] = {};
    for (int k0 = 0; k0 < K; k0 += 32) {
        uint4 av = *(const uint4*)&A[(size_t)(bm + ar) * K + k0 + ac];
        *(uint4*)&Alds[ar * 40 + ac] = av;
        #pragma unroll
        for (int i = 0; i < BN / 64; ++i) {
            int c = tid + 256 * i;
            int brow = c >> 2, bc = (c & 3) * 8;
            *(uint4*)&Blds[brow * 40 + bc] = *(const uint4*)&Wt[(size_t)brow * K + k0 + bc];
        }
        __syncthreads();
        bf16x8 af = *(const bf16x8*)&Alds[(wave * 16 + m16) * 40 + quad * 8];
        #pragma unroll
        for (int j = 0; j < NT; ++j) {
            bf16x8 bfr = *(const bf16x8*)&Blds[(j * 16 + m16) * 40 + quad * 8];
            acc[j] = __builtin_amdgcn_mfma_f32_16x16x32_bf16(af, bfr, acc[j], 0, 0, 0);
        }
        __syncthreads();
    }
    #pragma unroll
    for (int j = 0; j < NT; ++j) {
        int col = j * 16 + m16;
        float bb = bias[col];
        #pragma unroll
        for (int r = 0; r < 4; ++r) {
            int row = bm + wave * 16 + quad * 4 + r;
            C[(size_t)row * BN + col] = f2bf(acc[j][r] + bb);
        }
    }
}

// ---------------- SpMM over bf16 z (row-major), 4B packed edges ----------------
// bf16 residual state: MODE 0: hb = bf16(relu(s))
//                      MODE 1: hb = bf16(bf2f(hb) + relu(s)*dt)
//                      MODE 2: out = s (fp32)
template <int D, int MODE>
__global__ __launch_bounds__(256) void spmm_kernel(
        const int* __restrict__ offs, const unsigned int* __restrict__ edges,
        const unsigned short* __restrict__ z,
        float* __restrict__ out, unsigned short* __restrict__ hb,
        const float* __restrict__ dt_ptr, int n) {
    int r = (int)((blockIdx.x * blockDim.x + threadIdx.x) >> 6);
    int lane = threadIdx.x & 63;
    if (r >= n) return;
    r = __builtin_amdgcn_readfirstlane(r);
    const int s = offs[r], e = offs[r + 1];
    float acc0 = 0.f, acc1 = 0.f;
    int p = s;
    if (D == 128) {
        const unsigned int* z32 = (const unsigned int*)z;
        for (; p + 8 <= e; p += 8) {
            unsigned int ev[8], g[8];
            #pragma unroll
            for (int i = 0; i < 8; ++i) ev[i] = __builtin_nontemporal_load(edges + p + i);
            #pragma unroll
            for (int i = 0; i < 8; ++i)
                g[i] = z32[(size_t)(ev[i] >> 15) * 64 + lane];
            #pragma unroll
            for (int i = 0; i < 8; ++i) {
                float v = (float)(ev[i] & 0x7fffu) * VAL_DEC;
                acc0 = fmaf(v, bf2f(g[i] & 0xffffu), acc0);
                acc1 = fmaf(v, bf2f(g[i] >> 16), acc1);
            }
        }
        for (; p < e; ++p) {
            unsigned int ev = __builtin_nontemporal_load(edges + p);
            float v = (float)(ev & 0x7fffu) * VAL_DEC;
            unsigned int g = z32[(size_t)(ev >> 15) * 64 + lane];
            acc0 = fmaf(v, bf2f(g & 0xffffu), acc0);
            acc1 = fmaf(v, bf2f(g >> 16), acc1);
        }
        unsigned int* hbw = (unsigned int*)hb + (size_t)r * 64 + lane;
        if (MODE == 2) {
            float2 o; o.x = acc0; o.y = acc1;
            *(float2*)&out[(size_t)r * 128 + 2 * lane] = o;
        } else if (MODE == 0) {
            *hbw = pack2(fmaxf(acc0, 0.f), fmaxf(acc1, 0.f));
        } else {
            float dt = *dt_ptr;
            unsigned int cur = *hbw;
            float f0 = bf2f(cur & 0xffffu) + fmaxf(acc0, 0.f) * dt;
            float f1 = bf2f(cur >> 16)    + fmaxf(acc1, 0.f) * dt;
            *hbw = pack2(f0, f1);
        }
    } else {  // D == 64 (final layer, MODE 2)
        for (; p + 8 <= e; p += 8) {
            unsigned int ev[8];
            unsigned short g[8];
            #pragma unroll
            for (int i = 0; i < 8; ++i) ev[i] = __builtin_nontemporal_load(edges + p + i);
            #pragma unroll
            for (int i = 0; i < 8; ++i)
                g[i] = z[(size_t)(ev[i] >> 15) * 64 + lane];
            #pragma unroll
            for (int i = 0; i < 8; ++i)
                acc0 = fmaf((float)(ev[i] & 0x7fffu) * VAL_DEC, bf2f(g[i]), acc0);
        }
        for (; p < e; ++p) {
            unsigned int ev = __builtin_nontemporal_load(edges + p);
            acc0 = fmaf((float)(ev & 0x7fffu) * VAL_DEC,
                        bf2f((unsigned int)z[(size_t)(ev >> 15) * 64 + lane]), acc0);
        }
        out[(size_t)r * 64 + lane] = acc0;
    }
}

extern "C" void kernel_launch(void* const* d_in, const int* in_sizes, int n_in,
                              void* d_out, int out_size, void* d_ws, size_t ws_size,
                              hipStream_t stream) {
    const float* x    = (const float*)d_in[0];
    const int*   erow = (const int*)d_in[1];
    const int*   ecol = (const int*)d_in[2];
    const float* eval = (const float*)d_in[3];
    const float* w1   = (const float*)d_in[4];
    const float* b1   = (const float*)d_in[5];
    const float* wm   = (const float*)d_in[6];
    const float* bmp  = (const float*)d_in[7];
    const float* w2   = (const float*)d_in[8];
    const float* b2   = (const float*)d_in[9];
    const float* dt   = (const float*)d_in[10];

    const int N = in_sizes[0] / DIN;       // 40000
    const int E = in_sizes[1];             // 640000
    const int L = in_sizes[7] / HID;       // 2
    const int NB = (N + 255) >> 8;         // 157 buckets

    float* outp = (float*)d_out;

    char* ws = (char*)d_ws;
    auto carve = [&](size_t bytes) -> char* {
        char* p = ws;
        ws += (bytes + 255) & ~(size_t)255;
        return p;
    };
    int*            counts = (int*)carve((size_t)(NB * SB + 1) * 4);
    int*            starts = (int*)carve((size_t)(NB * SB + 1) * 4);
    int*            bsums  = (int*)carve(64 * 4);
    int*            offs   = (int*)carve((size_t)(N + 1) * 4);
    unsigned int*   bw     = (unsigned int*)carve((size_t)E * 4);
    unsigned char*  brr    = (unsigned char*)carve((size_t)E);
    unsigned int*   edges  = (unsigned int*)carve((size_t)E * 4);
    unsigned short* z      = (unsigned short*)carve((size_t)N * HID * 2);
    unsigned short* hb     = (unsigned short*)carve((size_t)N * HID * 2);
    unsigned short* w1t    = (unsigned short*)carve((size_t)HID * DIN * 2);
    unsigned short* wmt    = (unsigned short*)carve((size_t)L * HID * HID * 2);
    unsigned short* w2t    = (unsigned short*)carve((size_t)NCLS * HID * 2);

    const int nscan   = NB * SB;                 // 40192
    const int ntiles  = (nscan + 1023) / 1024;   // 40 (covers i==nscan)
    const int gemm_blocks = N / 64;              // 625
    const int spmm_blocks = (N + 3) / 4;         // 10000

    // --- CSR build (counting sort) + prep ---
    prep_hist_kernel<<<SB, 256, 0, stream>>>(w1, wm, w2, w1t, wmt, w2t, L,
                                             erow, counts, E, NB);
    scan_sums_kernel<<<ntiles, 1024, 0, stream>>>(counts, bsums, nscan);
    scan_fix_kernel<<<ntiles, 1024, 0, stream>>>(counts, bsums, starts, nscan, ntiles);
    // --- GEMM1 || bucket scatter ---
    mega_kernel<<<gemm_blocks + SB, 256, 0, stream>>>(
        x, w1t, b1, z, erow, ecol, eval, starts, bw, brr, E, NB, gemm_blocks);
    finalize_kernel<<<NB, 256, 0, stream>>>(starts, bw, brr, edges, offs, N, NB);

    spmm_kernel<HID, 0><<<spmm_blocks, 256, 0, stream>>>(offs, edges, z, nullptr, hb, nullptr, N);

    // --- middle residual layers ---
    for (int i = 0; i < L; ++i) {
        gemm_mfma_kernel<HID><<<gemm_blocks, 256, 0, stream>>>(
            hb, wmt + (size_t)i * HID * HID, bmp + (size_t)i * HID, z, HID);
        spmm_kernel<HID, 1><<<spmm_blocks, 256, 0, stream>>>(offs, edges, z, nullptr, hb, dt, N);
    }

    // --- output layer ---
    gemm_mfma_kernel<NCLS><<<gemm_blocks, 256, 0, stream>>>(hb, w2t, b2, z, HID);
    spmm_kernel<NCLS, 2><<<spmm_blocks, 256, 0, stream>>>(offs, edges, z, outp, nullptr, nullptr, N);
}